// Round 1
// baseline (322.869 us; speedup 1.0000x reference)
//
#include <hip/hip_runtime.h>

// Multi-scale deformable attention (Deformable-DETR), forward.
// value:              (bs, K, nh, D)        f32
// value_spatial_shapes:(L, 2)               i32
// sampling_locations: (bs, Q, nh, L, P, 2)  f32  in [0,1]
// attention_weights:  (bs, Q, nh, L, P)     f32
// out:                (bs, Q, nh*D)         f32  (head-major channels)

#define BS 2
#define NH 8
#define DD 32
#define LL 4
#define PP 4
#define GROUPS_PER_BLOCK 8   // 8 groups of 32 lanes = 256 threads

__global__ __launch_bounds__(256) void msda_fwd_kernel(
    const float* __restrict__ value,
    const int*   __restrict__ shapes,   // (L,2)
    const float* __restrict__ loc,      // (bs,Q,nh,L,P,2)
    const float* __restrict__ aw,       // (bs,Q,nh,L,P)
    float*       __restrict__ out,      // (bs,Q,nh*D)
    int Q, int K)
{
    const int gid  = blockIdx.x * GROUPS_PER_BLOCK + (threadIdx.x >> 5);
    const int lane = threadIdx.x & 31;
    const int total = BS * Q * NH;
    if (gid >= total) return;

    // gid = (b*Q + q)*NH + h
    const int h  = gid % NH;
    const int bq = gid / NH;
    const int q  = bq % Q;
    const int b  = bq / Q;

    const float* loc_base = loc + (size_t)gid * (LL * PP * 2);
    const float* aw_base  = aw  + (size_t)gid * (LL * PP);
    // value element for this (b, ·, h, lane): stride between keys = NH*DD
    const float* vbase = value + ((size_t)b * K * NH + h) * DD + lane;
    const int kstride = NH * DD;

    float acc = 0.0f;
    int start = 0;

    #pragma unroll
    for (int l = 0; l < LL; ++l) {
        const int H = shapes[2 * l];
        const int W = shapes[2 * l + 1];
        const float fH = (float)H, fW = (float)W;

        #pragma unroll
        for (int p = 0; p < PP; ++p) {
            const float lx = loc_base[(l * PP + p) * 2 + 0];
            const float ly = loc_base[(l * PP + p) * 2 + 1];
            const float w  = aw_base[l * PP + p];

            // align_corners=False unnormalize of grid=2*loc-1:
            // x = ((2*loc-1)+1)*W/2 - 0.5 = loc*W - 0.5
            const float x = lx * fW - 0.5f;
            const float y = ly * fH - 0.5f;
            const float x0f = floorf(x);
            const float y0f = floorf(y);
            const int x0 = (int)x0f, y0 = (int)y0f;
            const int x1 = x0 + 1,  y1 = y0 + 1;
            const float dx = x - x0f, dy = y - y0f;

            const float w00 = (1.0f - dx) * (1.0f - dy) * w;
            const float w01 = dx * (1.0f - dy) * w;
            const float w10 = (1.0f - dx) * dy * w;
            const float w11 = dx * dy * w;

            const bool vx0 = (x0 >= 0) & (x0 < W);
            const bool vx1 = (x1 >= 0) & (x1 < W);
            const bool vy0 = (y0 >= 0) & (y0 < H);
            const bool vy1 = (y1 >= 0) & (y1 < H);

            if (vy0) {
                const float* row = vbase + (size_t)(start + y0 * W) * kstride;
                if (vx0) acc = fmaf(w00, row[(size_t)x0 * kstride], acc);
                if (vx1) acc = fmaf(w01, row[(size_t)x1 * kstride], acc);
            }
            if (vy1) {
                const float* row = vbase + (size_t)(start + y1 * W) * kstride;
                if (vx0) acc = fmaf(w10, row[(size_t)x0 * kstride], acc);
                if (vx1) acc = fmaf(w11, row[(size_t)x1 * kstride], acc);
            }
        }
        start += H * W;
    }

    // out: (bs, Q, nh*D), head-major channels -> ((b*Q+q)*NH + h)*DD + lane
    out[(size_t)gid * DD + lane] = acc;
}

extern "C" void kernel_launch(void* const* d_in, const int* in_sizes, int n_in,
                              void* d_out, int out_size, void* d_ws, size_t ws_size,
                              hipStream_t stream) {
    const float* value  = (const float*)d_in[0];
    const int*   shapes = (const int*)d_in[1];
    const float* loc    = (const float*)d_in[2];
    const float* aw     = (const float*)d_in[3];
    float*       out    = (float*)d_out;

    const int K = in_sizes[0] / (BS * NH * DD);
    const int Q = in_sizes[3] / (BS * NH * LL * PP);

    const int total_groups = BS * Q * NH;
    const int blocks = (total_groups + GROUPS_PER_BLOCK - 1) / GROUPS_PER_BLOCK;

    msda_fwd_kernel<<<blocks, 256, 0, stream>>>(value, shapes, loc, aw, out, Q, K);
}

// Round 4
// 131.305 us; speedup vs baseline: 2.4589x; 2.4589x over previous
//
#include <hip/hip_runtime.h>

// Multi-scale deformable attention (Deformable-DETR), forward. All shapes static:
// value: (2, 13294, 8, 32) f32 | loc: (2,13294,8,4,4,2) f32 | aw: (2,13294,8,4,4) f32
// out:   (2, 13294, 256) f32 (head-major channels)

#define BS 2
#define NH 8
#define DD 32
#define LL 4
#define PP 4
#define QQ 13294
#define KK 13294
#define LPG 8    // lanes per group; each lane holds 4 channels (float4)
#define GPB 32   // groups per 256-thread block; grid is exact (212704/32 = 6647)

typedef float f32x2 __attribute__((ext_vector_type(2)));
typedef float f32x4 __attribute__((ext_vector_type(4)));

__global__ __launch_bounds__(256) void msda_fwd_kernel(
    const f32x4* __restrict__ value4,  // (bs,K,nh,8) f32x4
    const f32x2* __restrict__ loc2,    // (bs,Q,nh,L,P) f32x2
    const float* __restrict__ aw,      // (bs,Q,nh,L,P)
    f32x4*       __restrict__ out4)    // (bs,Q,nh,8) f32x4
{
    constexpr int Hs[4]     = {100, 50, 25, 13};
    constexpr int Ws[4]     = {100, 50, 25, 13};
    constexpr int starts[4] = {0, 10000, 12500, 13125};

    // Group order is (b, h, q): a dispatch window of consecutive blocks gathers
    // within one ~1.7 MB (b,h) value slab, which fits a 4 MB XCD L2.
    const int gid  = blockIdx.x * GPB + (threadIdx.x >> 3);
    const int lane = threadIdx.x & (LPG - 1);

    const int q  = gid % QQ;
    const int bh = gid / QQ;
    const int h  = bh % NH;
    const int b  = bh / NH;

    const size_t lp_base = ((size_t)(b * QQ + q) * NH + h) * (LL * PP);
    const f32x2* lp = loc2 + lp_base;
    const float* wp = aw   + lp_base;

    // f32x4 element for (b, key, h, lane): key stride = NH*DD/4 = 64 vectors
    const f32x4* vbase = value4 + ((size_t)b * KK * NH + h) * (DD / 4) + lane;

    f32x4 acc = {0.0f, 0.0f, 0.0f, 0.0f};

    #pragma unroll
    for (int l = 0; l < LL; ++l) {
        const int H = Hs[l], W = Ws[l];
        const float fH = (float)H, fW = (float)W;
        #pragma unroll
        for (int p = 0; p < PP; ++p) {
            const int s = l * PP + p;
            // loc/aw are streamed exactly once per group: nontemporal keeps L2 for value
            const f32x2 lxy = __builtin_nontemporal_load(&lp[s]);
            const float w   = __builtin_nontemporal_load(&wp[s]);

            // align_corners=False, padding zeros: x = loc_x*W - 0.5
            const float x = lxy.x * fW - 0.5f;
            const float y = lxy.y * fH - 0.5f;
            const float x0f = floorf(x), y0f = floorf(y);
            const float dx = x - x0f, dy = y - y0f;
            const int x0 = (int)x0f, y0 = (int)y0f;
            const int x1 = x0 + 1,  y1 = y0 + 1;

            const float mx0 = ((unsigned)x0 < (unsigned)W) ? 1.0f : 0.0f;
            const float mx1 = ((unsigned)x1 < (unsigned)W) ? 1.0f : 0.0f;
            const float my0 = ((unsigned)y0 < (unsigned)H) ? 1.0f : 0.0f;
            const float my1 = ((unsigned)y1 < (unsigned)H) ? 1.0f : 0.0f;

            const int cx0 = min(max(x0, 0), W - 1);
            const int cx1 = min(max(x1, 0), W - 1);
            const int cy0 = min(max(y0, 0), H - 1);
            const int cy1 = min(max(y1, 0), H - 1);

            const float w00 = (1.0f - dx) * (1.0f - dy) * w * mx0 * my0;
            const float w01 = dx * (1.0f - dy) * w * mx1 * my0;
            const float w10 = (1.0f - dx) * dy * w * mx0 * my1;
            const float w11 = dx * dy * w * mx1 * my1;

            const int r0 = starts[l] + cy0 * W;
            const int r1 = starts[l] + cy1 * W;
            const f32x4 v00 = vbase[(size_t)(r0 + cx0) * (NH * DD / 4)];
            const f32x4 v01 = vbase[(size_t)(r0 + cx1) * (NH * DD / 4)];
            const f32x4 v10 = vbase[(size_t)(r1 + cx0) * (NH * DD / 4)];
            const f32x4 v11 = vbase[(size_t)(r1 + cx1) * (NH * DD / 4)];

            acc.x = fmaf(w00, v00.x, acc.x);
            acc.y = fmaf(w00, v00.y, acc.y);
            acc.z = fmaf(w00, v00.z, acc.z);
            acc.w = fmaf(w00, v00.w, acc.w);
            acc.x = fmaf(w01, v01.x, acc.x);
            acc.y = fmaf(w01, v01.y, acc.y);
            acc.z = fmaf(w01, v01.z, acc.z);
            acc.w = fmaf(w01, v01.w, acc.w);
            acc.x = fmaf(w10, v10.x, acc.x);
            acc.y = fmaf(w10, v10.y, acc.y);
            acc.z = fmaf(w10, v10.z, acc.z);
            acc.w = fmaf(w10, v10.w, acc.w);
            acc.x = fmaf(w11, v11.x, acc.x);
            acc.y = fmaf(w11, v11.y, acc.y);
            acc.z = fmaf(w11, v11.z, acc.z);
            acc.w = fmaf(w11, v11.w, acc.w);
        }
    }

    // out: (bs,Q,nh,8) f32x4; streamed once -> nontemporal store
    __builtin_nontemporal_store(acc, &out4[((size_t)(b * QQ + q) * NH + h) * (DD / 4) + lane]);
}

extern "C" void kernel_launch(void* const* d_in, const int* in_sizes, int n_in,
                              void* d_out, int out_size, void* d_ws, size_t ws_size,
                              hipStream_t stream) {
    const f32x4* value4 = (const f32x4*)d_in[0];
    const f32x2* loc2   = (const f32x2*)d_in[2];
    const float* aw     = (const float*)d_in[3];
    f32x4*       out4   = (f32x4*)d_out;

    const int total_groups = BS * NH * QQ;   // 212704, exactly 6647 * GPB
    const int blocks = total_groups / GPB;   // 6647, no tail

    msda_fwd_kernel<<<blocks, 256, 0, stream>>>(value4, loc2, aw, out4);
}